// Round 12
// baseline (165.254 us; speedup 1.0000x reference)
//
#include <hip/hip_runtime.h>
#include <math.h>

#define BATCH    128
#define N_ATOMS  4096
#define NB       4095
#define NA       4094
#define NT       4093
#define FSTRIDE  184185                // floats per sample
#define ROWS     20465                 // rows of 9 floats per sample
#define CROWS    12288                 // coord elements (3*N_ATOMS)
#define BROWS    12285                 // bond elements  (3*NB)
#define AROWS    16376                 // angle elements (4*NA)
#define EPSV     1e-8f
#define WAVES    16

// d_ws byte offsets (all 16B-aligned). Column streams, element R at index R.
#define WS_CW_B  0                     // float [128][12288]  = 6.29 MB
#define WS_BW_B  6291456               // u16   [128][12288]  = 3.15 MB
#define WS_AW_B  9437184               // u16   [128][16384]  = 4.19 MB
#define WS_TW_B  13631488              // u16   [128][20472]  = 5.24 MB  (end ~18.9 MB)

// 4-byte-aligned float4 (row fields at byte 36R+20 are only dword-aligned).
typedef float float4a __attribute__((ext_vector_type(4), aligned(4)));

// ============ K1: pure-streaming extraction, max parallelism ============
// 2048 blocks x 256 threads, zero LDS, no barriers -> 32 waves/CU, 5
// independent predicated loads in flight per thread. One dwordx4 per row
// delivers (coord,bond,angle,tor)[R]; stores are coalesced column streams.
__global__ __launch_bounds__(256) void
extract_k(const float* __restrict__ F, float* __restrict__ ws)
{
    const int b     = blockIdx.x;
    const int x     = b & 7;             // XCD slot
    const int g     = b >> 3;            // 0..255
    const int s     = (g & 15) * 8 + x;  // sample, XCD-pinned (K2 uses same map)
    const int slice = g >> 4;            // 0..15, 1280 rows each
    const size_t sbase = (size_t)s * FSTRIDE;

    float*          __restrict__ cw = (float*)((char*)ws + WS_CW_B) + (size_t)s * 12288;
    unsigned short* __restrict__ bw = (unsigned short*)((char*)ws + WS_BW_B) + (size_t)s * 12288;
    unsigned short* __restrict__ aw = (unsigned short*)((char*)ws + WS_AW_B) + (size_t)s * 16384;
    unsigned short* __restrict__ tw = (unsigned short*)((char*)ws + WS_TW_B) + (size_t)s * 20472;

    const int lo = slice * 1280;
    int  r[5]; bool ok[5]; float4a v[5];
    #pragma unroll
    for (int k = 0; k < 5; ++k) {
        r[k]  = lo + (int)threadIdx.x + 256 * k;
        ok[k] = (r[k] < ROWS);
        if (ok[k]) v[k] = *(const float4a*)(F + sbase + (size_t)9 * r[k] + 5);
    }
    #pragma unroll
    for (int k = 0; k < 5; ++k) {
        if (!ok[k]) continue;
        const int R = r[k];
        if (R < CROWS) cw[R] = v[k].x;
        if (R < BROWS) bw[R] = (unsigned short)(int)v[k].y;
        if (R < AROWS) aw[R] = (unsigned short)(int)v[k].z;
        tw[R] = (unsigned short)(int)v[k].w;
    }
}

// ============ K2: compute from compact streams ============
#define THREADS 1024
__global__ __launch_bounds__(THREADS, 1) void
energy_k(const float* __restrict__ ws,
         const float* __restrict__ bond_type,   // 15 x 2
         const float* __restrict__ angle_type,  // 13 x 2
         const float* __restrict__ tor_type,    // 25 x 2
         const int*   __restrict__ multiplicity,// 25
         const float* __restrict__ opt_pars,    // 47
         float*       __restrict__ out)         // B x 3
{
    __shared__ float scc[CROWS];        // coords, atom a comp c at scc[3a+c]
    __shared__ float sbt[30], sat[26], stt[50], smu[25];
    __shared__ float sred[WAVES * 2];

    const int b   = blockIdx.x;
    const int x   = b & 7;
    const int g   = b >> 3;             // 0..31
    const int s   = (g & 15) * 8 + x;   // sample, same XCD slot as K1 writer
    const int p   = g >> 4;             // 0: torsions  1: bonds + angles
    const int tid = threadIdx.x;
    const int w   = tid >> 6;
    const int l   = tid & 63;

    if (tid < 30)                      sbt[tid]       = bond_type[tid];
    else if (tid >= 32 && tid < 58)    sat[tid - 32]  = angle_type[tid - 32];
    else if (tid >= 64 && tid < 114)   stt[tid - 64]  = tor_type[tid - 64];
    else if (tid >= 128 && tid < 153)  smu[tid - 128] = (float)multiplicity[tid - 128];

    {   // coalesced coord staging: 3 float4 per thread
        const float4* __restrict__ c4 =
            (const float4*)((const char*)ws + WS_CW_B + (size_t)s * 12288 * 4);
        #pragma unroll
        for (int i = 0; i < 3; ++i)
            ((float4*)scc)[tid + 1024 * i] = c4[tid + 1024 * i];
    }
    __syncthreads();

    float eA = 0.f, eB = 0.f;           // p0: eA=tor | p1: eA=bond eB=angle
    if (p) {
        const unsigned short* __restrict__ bwp =
            (const unsigned short*)((const char*)ws + WS_BW_B) + (size_t)s * 12288;
        for (int i = tid; i < NB; i += THREADS) {
            const int a0 = bwp[3 * i + 0];
            const int a1 = bwp[3 * i + 1];
            const int bt = bwp[3 * i + 2];
            const float dx = scc[3 * a0 + 0] - scc[3 * a1 + 0];
            const float dy = scc[3 * a0 + 1] - scc[3 * a1 + 1];
            const float dz = scc[3 * a0 + 2] - scc[3 * a1 + 2];
            const float rr = sqrtf(dx * dx + dy * dy + dz * dz + EPSV);
            const float t0 = rr - sbt[bt * 2 + 1];
            eA += sbt[bt * 2 + 0] * t0 * t0;
        }
        const ushort4* __restrict__ awp =
            (const ushort4*)((const char*)ws + WS_AW_B + (size_t)s * 16384 * 2);
        for (int i = tid; i < NA; i += THREADS) {
            const ushort4 u = awp[i];
            const int a0 = u.x, a1 = u.y, a2 = u.z, at = u.w;
            const float v1x = scc[3 * a0 + 0] - scc[3 * a1 + 0];
            const float v1y = scc[3 * a0 + 1] - scc[3 * a1 + 1];
            const float v1z = scc[3 * a0 + 2] - scc[3 * a1 + 2];
            const float v2x = scc[3 * a2 + 0] - scc[3 * a1 + 0];
            const float v2y = scc[3 * a2 + 1] - scc[3 * a1 + 1];
            const float v2z = scc[3 * a2 + 2] - scc[3 * a1 + 2];
            const float d12 = v1x * v2x + v1y * v2y + v1z * v2z;
            const float n1  = sqrtf(v1x * v1x + v1y * v1y + v1z * v1z + EPSV);
            const float n2  = sqrtf(v2x * v2x + v2y * v2y + v2z * v2z + EPSV);
            float cosang = d12 / (n1 * n2);
            cosang = fminf(fmaxf(cosang, -1.0f + 1e-6f), 1.0f - 1e-6f);
            const float t0 = acosf(cosang) - sat[at * 2 + 1];
            eB += sat[at * 2 + 0] * t0 * t0;
        }
    } else {
        const unsigned short* __restrict__ twp =
            (const unsigned short*)((const char*)ws + WS_TW_B) + (size_t)s * 20472;
        for (int i = tid; i < NT; i += THREADS) {
            const int ai = twp[5 * i + 0];
            const int aj = twp[5 * i + 1];
            const int ak = twp[5 * i + 2];
            const int al = twp[5 * i + 3];
            const int tt = twp[5 * i + 4];
            const float b1x = scc[3*aj+0] - scc[3*ai+0];
            const float b1y = scc[3*aj+1] - scc[3*ai+1];
            const float b1z = scc[3*aj+2] - scc[3*ai+2];
            const float b2x = scc[3*ak+0] - scc[3*aj+0];
            const float b2y = scc[3*ak+1] - scc[3*aj+1];
            const float b2z = scc[3*ak+2] - scc[3*aj+2];
            const float b3x = scc[3*al+0] - scc[3*ak+0];
            const float b3y = scc[3*al+1] - scc[3*ak+1];
            const float b3z = scc[3*al+2] - scc[3*ak+2];
            const float n1x = b1y*b2z - b1z*b2y;
            const float n1y = b1z*b2x - b1x*b2z;
            const float n1z = b1x*b2y - b1y*b2x;
            const float n2x = b2y*b3z - b2z*b3y;
            const float n2y = b2z*b3x - b2x*b3z;
            const float n2z = b2x*b3y - b2y*b3x;
            const float inv = 1.0f / sqrtf(b2x*b2x + b2y*b2y + b2z*b2z + EPSV);
            const float bnx = b2x * inv, bny = b2y * inv, bnz = b2z * inv;
            const float m1x = n1y*bnz - n1z*bny;
            const float m1y = n1z*bnx - n1x*bnz;
            const float m1z = n1x*bny - n1y*bnx;
            const float phi = atan2f(m1x*n2x + m1y*n2y + m1z*n2z,
                                     n1x*n2x + n1y*n2y + n1z*n2z);
            eA += stt[tt * 2 + 0] * (1.0f + cosf(smu[tt] * phi - stt[tt * 2 + 1]));
        }
    }

    for (int off = 32; off > 0; off >>= 1) {
        eA += __shfl_down(eA, off);
        eB += __shfl_down(eB, off);
    }
    if (l == 0) { sred[w * 2 + 0] = eA; sred[w * 2 + 1] = eB; }
    __syncthreads();
    if (tid == 0) {
        float rA = 0.f, rB = 0.f;
        for (int i = 0; i < WAVES; ++i) { rA += sred[i * 2]; rB += sred[i * 2 + 1]; }
        if (p) {
            out[s * 3 + 0] = opt_pars[0] * rA;   // bonds
            out[s * 3 + 1] = opt_pars[1] * rB;   // angles
        } else {
            out[s * 3 + 2] = opt_pars[2] * rA;   // torsions
        }
    }
}

extern "C" void kernel_launch(void* const* d_in, const int* in_sizes, int n_in,
                              void* d_out, int out_size, void* d_ws, size_t ws_size,
                              hipStream_t stream) {
    const float* F            = (const float*)d_in[0];
    // d_in[1] = lengths (constant, unused)
    const float* bond_type    = (const float*)d_in[2];
    const float* angle_type   = (const float*)d_in[3];
    const float* tor_type     = (const float*)d_in[4];
    const int*   multiplicity = (const int*)  d_in[5];
    const float* opt_pars     = (const float*)d_in[6];
    float* out = (float*)d_out;
    float* ws  = (float*)d_ws;

    // out: every element written exactly once by plain stores -> no memset.
    extract_k<<<dim3(2048), dim3(256), 0, stream>>>(F, ws);
    energy_k<<<dim3(256), dim3(THREADS), 0, stream>>>(
        ws, bond_type, angle_type, tor_type, multiplicity, opt_pars, out);
}

// Round 13
// 164.998 us; speedup vs baseline: 1.0016x; 1.0016x over previous
//
#include <hip/hip_runtime.h>
#include <math.h>

#define BATCH    128
#define N_ATOMS  4096
#define NB       4095
#define NA       4094
#define NT       4093
#define FSTRIDE  184185                // floats per sample
#define ROWS     20465                 // rows of 9 floats per sample
#define CROWS    12288                 // coord elements (3*N_ATOMS)
#define BROWS    12285                 // bond elements  (3*NB)
#define AROWS    16376                 // angle elements (4*NA)
#define EPSV     1e-8f
#define THREADS  1024
#define WAVES    16
#define TPR      120                   // rows per tile (2 rows per lane)
#define NTIL     171                   // ceil(20465/120)

// 4-byte-aligned float4 (row fields at float offset 9R+5 are dword-aligned only).
typedef float float4a __attribute__((ext_vector_type(4), aligned(4)));

// ONE block per sample: stream the sample's rows exactly once, extracting all
// four column streams (zero-decode: element R of each stream lands at LDS
// offset R), then compute all three energy terms in the same block.
// 94 MB chip-wide compulsory traffic, no twin re-fetch (R11 paid ~169 MB).
__global__ __launch_bounds__(THREADS, 1) void
local_energy_v13(const float* __restrict__ F,
                 const float* __restrict__ bond_type,   // 15 x 2
                 const float* __restrict__ angle_type,  // 13 x 2
                 const float* __restrict__ tor_type,    // 25 x 2
                 const int*   __restrict__ multiplicity,// 25
                 const float* __restrict__ opt_pars,    // 47
                 float*       __restrict__ out)         // B x 3
{
    __shared__ float          scc[CROWS];       // 48 KB  coords: atom a comp c at scc[3a+c]
    __shared__ unsigned short sbB[BROWS + 1];   // 24 KB
    __shared__ unsigned short sbA[AROWS];       // 32 KB
    __shared__ unsigned short sbT[ROWS + 1];    // 40 KB
    __shared__ float sbt[30], sat[26], stt[50], smu[25];
    __shared__ float sred[WAVES * 3];

    const int s   = blockIdx.x;        // sample 0..127 (one block per sample)
    const int tid = threadIdx.x;
    const int w   = tid >> 6;          // wave 0..15
    const int l   = tid & 63;          // lane
    const size_t sbase = (size_t)s * FSTRIDE;

    if (tid < 30)                      sbt[tid]       = bond_type[tid];
    else if (tid >= 32 && tid < 58)    sat[tid - 32]  = angle_type[tid - 32];
    else if (tid >= 64 && tid < 114)   stt[tid - 64]  = tor_type[tid - 64];
    else if (tid >= 128 && tid < 153)  smu[tid - 128] = (float)multiplicity[tid - 128];

    // ======== Phase A: single streaming pass, extract ALL columns ========
    // Row R: one dwordx4 at 9R+5 = (coord[R], bond[R], angle[R], tor[R]).
    // Lane l handles rows 120t+2l, +2l+1 -> packed pair stores, no divmod,
    // no scratch, no fences.
    for (int t = w; t < NTIL; t += WAVES) {
        const int R0 = TPR * t + 2 * l;          // even
        const int R1 = R0 + 1;
        float4a v0, v1;
        const bool ok0 = (R0 < ROWS);
        const bool ok1 = (R1 < ROWS);
        if (ok0) v0 = *(const float4a*)(F + sbase + (size_t)9 * R0 + 5);
        if (ok1) v1 = *(const float4a*)(F + sbase + (size_t)9 * R1 + 5);

        // coords (CROWS even -> pair store always in-bounds together)
        if (R1 < CROWS) {
            float2 c2; c2.x = v0.x; c2.y = v1.x;
            *(float2*)(scc + R0) = c2;
        }
        // bonds (BROWS odd -> tail single)
        if (R1 < BROWS) {
            unsigned pk = (unsigned)(unsigned short)(int)v0.y
                        | ((unsigned)(unsigned short)(int)v1.y << 16);
            *(unsigned*)(sbB + R0) = pk;
        } else if (R0 < BROWS) {
            sbB[R0] = (unsigned short)(int)v0.y;
        }
        // angles (AROWS even)
        if (R1 < AROWS) {
            unsigned pk = (unsigned)(unsigned short)(int)v0.z
                        | ((unsigned)(unsigned short)(int)v1.z << 16);
            *(unsigned*)(sbA + R0) = pk;
        }
        // torsions (ROWS odd -> tail single)
        if (ok1) {
            unsigned pk = (unsigned)(unsigned short)(int)v0.w
                        | ((unsigned)(unsigned short)(int)v1.w << 16);
            *(unsigned*)(sbT + R0) = pk;
        } else if (ok0) {
            sbT[R0] = (unsigned short)(int)v0.w;
        }
    }
    __syncthreads();

    // ======== Phase B: all three terms from compact LDS ========
    float e_bond = 0.f, e_ang = 0.f, e_tor = 0.f;

    for (int i = tid; i < NB; i += THREADS) {
        const int a0 = sbB[3 * i + 0];
        const int a1 = sbB[3 * i + 1];
        const int bt = sbB[3 * i + 2];
        const float dx = scc[3 * a0 + 0] - scc[3 * a1 + 0];
        const float dy = scc[3 * a0 + 1] - scc[3 * a1 + 1];
        const float dz = scc[3 * a0 + 2] - scc[3 * a1 + 2];
        const float r  = sqrtf(dx * dx + dy * dy + dz * dz + EPSV);
        const float t0 = r - sbt[bt * 2 + 1];
        e_bond += sbt[bt * 2 + 0] * t0 * t0;
    }
    for (int i = tid; i < NA; i += THREADS) {
        const int a0 = sbA[4 * i + 0];
        const int a1 = sbA[4 * i + 1];
        const int a2 = sbA[4 * i + 2];
        const int at = sbA[4 * i + 3];
        const float v1x = scc[3 * a0 + 0] - scc[3 * a1 + 0];
        const float v1y = scc[3 * a0 + 1] - scc[3 * a1 + 1];
        const float v1z = scc[3 * a0 + 2] - scc[3 * a1 + 2];
        const float v2x = scc[3 * a2 + 0] - scc[3 * a1 + 0];
        const float v2y = scc[3 * a2 + 1] - scc[3 * a1 + 1];
        const float v2z = scc[3 * a2 + 2] - scc[3 * a1 + 2];
        const float d12 = v1x * v2x + v1y * v2y + v1z * v2z;
        const float n1  = sqrtf(v1x * v1x + v1y * v1y + v1z * v1z + EPSV);
        const float n2  = sqrtf(v2x * v2x + v2y * v2y + v2z * v2z + EPSV);
        float cosang = d12 / (n1 * n2);
        cosang = fminf(fmaxf(cosang, -1.0f + 1e-6f), 1.0f - 1e-6f);
        const float t0 = acosf(cosang) - sat[at * 2 + 1];
        e_ang += sat[at * 2 + 0] * t0 * t0;
    }
    for (int i = tid; i < NT; i += THREADS) {
        const int ai = sbT[5 * i + 0];
        const int aj = sbT[5 * i + 1];
        const int ak = sbT[5 * i + 2];
        const int al = sbT[5 * i + 3];
        const int tt = sbT[5 * i + 4];
        const float b1x = scc[3*aj+0] - scc[3*ai+0];
        const float b1y = scc[3*aj+1] - scc[3*ai+1];
        const float b1z = scc[3*aj+2] - scc[3*ai+2];
        const float b2x = scc[3*ak+0] - scc[3*aj+0];
        const float b2y = scc[3*ak+1] - scc[3*aj+1];
        const float b2z = scc[3*ak+2] - scc[3*aj+2];
        const float b3x = scc[3*al+0] - scc[3*ak+0];
        const float b3y = scc[3*al+1] - scc[3*ak+1];
        const float b3z = scc[3*al+2] - scc[3*ak+2];
        const float n1x = b1y*b2z - b1z*b2y;
        const float n1y = b1z*b2x - b1x*b2z;
        const float n1z = b1x*b2y - b1y*b2x;
        const float n2x = b2y*b3z - b2z*b3y;
        const float n2y = b2z*b3x - b2x*b3z;
        const float n2z = b2x*b3y - b2y*b3x;
        const float inv = 1.0f / sqrtf(b2x*b2x + b2y*b2y + b2z*b2z + EPSV);
        const float bnx = b2x * inv, bny = b2y * inv, bnz = b2z * inv;
        const float m1x = n1y*bnz - n1z*bny;
        const float m1y = n1z*bnx - n1x*bnz;
        const float m1z = n1x*bny - n1y*bnx;
        const float phi = atan2f(m1x*n2x + m1y*n2y + m1z*n2z,
                                 n1x*n2x + n1y*n2y + n1z*n2z);
        e_tor += stt[tt * 2 + 0] * (1.0f + cosf(smu[tt] * phi - stt[tt * 2 + 1]));
    }

    // ======== Reduction + plain stores (each element written once) ========
    for (int off = 32; off > 0; off >>= 1) {
        e_bond += __shfl_down(e_bond, off);
        e_ang  += __shfl_down(e_ang,  off);
        e_tor  += __shfl_down(e_tor,  off);
    }
    if (l == 0) {
        sred[w * 3 + 0] = e_bond;
        sred[w * 3 + 1] = e_ang;
        sred[w * 3 + 2] = e_tor;
    }
    __syncthreads();
    if (tid == 0) {
        float eb = 0.f, ea = 0.f, et = 0.f;
        for (int i = 0; i < WAVES; ++i) {
            eb += sred[i * 3 + 0];
            ea += sred[i * 3 + 1];
            et += sred[i * 3 + 2];
        }
        out[s * 3 + 0] = opt_pars[0] * eb;
        out[s * 3 + 1] = opt_pars[1] * ea;
        out[s * 3 + 2] = opt_pars[2] * et;
    }
}

extern "C" void kernel_launch(void* const* d_in, const int* in_sizes, int n_in,
                              void* d_out, int out_size, void* d_ws, size_t ws_size,
                              hipStream_t stream) {
    const float* F            = (const float*)d_in[0];
    // d_in[1] = lengths (constant, unused)
    const float* bond_type    = (const float*)d_in[2];
    const float* angle_type   = (const float*)d_in[3];
    const float* tor_type     = (const float*)d_in[4];
    const int*   multiplicity = (const int*)  d_in[5];
    const float* opt_pars     = (const float*)d_in[6];
    float* out = (float*)d_out;

    // Every out element written exactly once by plain stores -> no memset.
    local_energy_v13<<<dim3(BATCH), dim3(THREADS), 0, stream>>>(
        F, bond_type, angle_type, tor_type, multiplicity, opt_pars, out);
}

// Round 14
// 157.918 us; speedup vs baseline: 1.0465x; 1.0448x over previous
//
#include <hip/hip_runtime.h>
#include <math.h>

#define BATCH    128
#define N_ATOMS  4096
#define NB       4095
#define NA       4094
#define NT       4093
#define FSTRIDE  184185                // floats per sample
#define ROWS     20465                 // rows of 9 floats per sample
#define CROWS    12288                 // coord elements (3*N_ATOMS)
#define BROWS    12285                 // bond elements  (3*NB)
#define AROWS    16376                 // angle elements (4*NA)
#define EPSV     1e-8f
#define THREADS  1024
#define WAVES    16
#define TPR      128                   // rows per tile: lane l -> rows 128t+l, 128t+64+l
#define NTIL     160                   // ceil(20465/128)
#define NTIL_BA  128                   // rows < AROWS=16376 covered by 128 tiles (16384)

// 4-byte-aligned float4 (fields of row R start at float 9R+5, dword-aligned only).
typedef float float4a __attribute__((ext_vector_type(4), aligned(4)));

__global__ __launch_bounds__(THREADS, 1) void
local_energy_v14(const float* __restrict__ F,
                 const float* __restrict__ bond_type,   // 15 x 2
                 const float* __restrict__ angle_type,  // 13 x 2
                 const float* __restrict__ tor_type,    // 25 x 2
                 const int*   __restrict__ multiplicity,// 25
                 const float* __restrict__ opt_pars,    // 47
                 float*       __restrict__ out)         // B x 3
{
    __shared__ float          scc[CROWS];   // coords: atom a comp c at scc[3a+c]
    __shared__ unsigned short sbB[BROWS + 1];
    __shared__ unsigned short sbA[AROWS];
    __shared__ unsigned short sbT[ROWS + 1];
    __shared__ float sbt[30], sat[26], stt[50], smu[25];
    __shared__ float sred[WAVES * 2];

    const int b   = blockIdx.x;
    const int x   = b & 7;             // XCD slot (twins share it -> L2/L3 dedup)
    const int g   = b >> 3;            // 0..31
    const int s   = (g & 15) * 8 + x;  // sample 0..127
    const int p   = g >> 4;            // 0: torsions   1: bonds + angles
    const int tid = threadIdx.x;
    const int w   = tid >> 6;
    const int l   = tid & 63;
    const size_t sbase = (size_t)s * FSTRIDE;

    if (tid < 30)                      sbt[tid]       = bond_type[tid];
    else if (tid >= 32 && tid < 58)    sat[tid - 32]  = angle_type[tid - 32];
    else if (tid >= 64 && tid < 114)   stt[tid - 64]  = tor_type[tid - 64];
    else if (tid >= 128 && tid < 153)  smu[tid - 128] = (float)multiplicity[tid - 128];

    // ======== Phase A: stream rows with 36B-lane-stride loads ========
    // Row R: dwordx4 at 9R+5 = (coord,bond,angle,tor)[R] -> LDS offset R.
    // Lane l takes rows 128t+l and 128t+64+l: within one wave load, lanes sit
    // at 36B stride -> ~37 L1 line-probes per instruction instead of ~100 for
    // the 72B-stride pairing (TA dedups same-line lanes). R13 showed TA/L1
    // address processing is the bottleneck (DS<10%, VALU<8%, HBM 10%).
    const int tmax = p ? NTIL_BA : NTIL;
    for (int t = w; t < tmax; t += WAVES) {
        const int R0 = TPR * t + l;
        const int R1 = R0 + 64;
        float4a v0, v1;
        const bool ok0 = (R0 < ROWS);
        const bool ok1 = (R1 < ROWS);
        if (ok0) v0 = *(const float4a*)(F + sbase + (size_t)9 * R0 + 5);
        if (ok1) v1 = *(const float4a*)(F + sbase + (size_t)9 * R1 + 5);

        if (ok0) {
            if (R0 < CROWS) scc[R0] = v0.x;
            if (p) {
                if (R0 < BROWS) sbB[R0] = (unsigned short)(int)v0.y;
                if (R0 < AROWS) sbA[R0] = (unsigned short)(int)v0.z;
            } else {
                sbT[R0] = (unsigned short)(int)v0.w;
            }
        }
        if (ok1) {
            if (R1 < CROWS) scc[R1] = v1.x;
            if (p) {
                if (R1 < BROWS) sbB[R1] = (unsigned short)(int)v1.y;
                if (R1 < AROWS) sbA[R1] = (unsigned short)(int)v1.z;
            } else {
                sbT[R1] = (unsigned short)(int)v1.w;
            }
        }
    }
    __syncthreads();

    // ======== Phase B: compute from compact LDS (term-split twins) ========
    float eA = 0.f, eB = 0.f;          // p0: eA=tor | p1: eA=bond, eB=angle
    if (p) {
        for (int i = tid; i < NB; i += THREADS) {
            const int a0 = sbB[3 * i + 0];
            const int a1 = sbB[3 * i + 1];
            const int bt = sbB[3 * i + 2];
            const float dx = scc[3 * a0 + 0] - scc[3 * a1 + 0];
            const float dy = scc[3 * a0 + 1] - scc[3 * a1 + 1];
            const float dz = scc[3 * a0 + 2] - scc[3 * a1 + 2];
            const float r  = sqrtf(dx * dx + dy * dy + dz * dz + EPSV);
            const float t0 = r - sbt[bt * 2 + 1];
            eA += sbt[bt * 2 + 0] * t0 * t0;
        }
        for (int i = tid; i < NA; i += THREADS) {
            const int a0 = sbA[4 * i + 0];
            const int a1 = sbA[4 * i + 1];
            const int a2 = sbA[4 * i + 2];
            const int at = sbA[4 * i + 3];
            const float v1x = scc[3 * a0 + 0] - scc[3 * a1 + 0];
            const float v1y = scc[3 * a0 + 1] - scc[3 * a1 + 1];
            const float v1z = scc[3 * a0 + 2] - scc[3 * a1 + 2];
            const float v2x = scc[3 * a2 + 0] - scc[3 * a1 + 0];
            const float v2y = scc[3 * a2 + 1] - scc[3 * a1 + 1];
            const float v2z = scc[3 * a2 + 2] - scc[3 * a1 + 2];
            const float d12 = v1x * v2x + v1y * v2y + v1z * v2z;
            const float n1  = sqrtf(v1x * v1x + v1y * v1y + v1z * v1z + EPSV);
            const float n2  = sqrtf(v2x * v2x + v2y * v2y + v2z * v2z + EPSV);
            float cosang = d12 / (n1 * n2);
            cosang = fminf(fmaxf(cosang, -1.0f + 1e-6f), 1.0f - 1e-6f);
            const float t0 = acosf(cosang) - sat[at * 2 + 1];
            eB += sat[at * 2 + 0] * t0 * t0;
        }
    } else {
        for (int i = tid; i < NT; i += THREADS) {
            const int ai = sbT[5 * i + 0];
            const int aj = sbT[5 * i + 1];
            const int ak = sbT[5 * i + 2];
            const int al = sbT[5 * i + 3];
            const int tt = sbT[5 * i + 4];
            const float b1x = scc[3*aj+0] - scc[3*ai+0];
            const float b1y = scc[3*aj+1] - scc[3*ai+1];
            const float b1z = scc[3*aj+2] - scc[3*ai+2];
            const float b2x = scc[3*ak+0] - scc[3*aj+0];
            const float b2y = scc[3*ak+1] - scc[3*aj+1];
            const float b2z = scc[3*ak+2] - scc[3*aj+2];
            const float b3x = scc[3*al+0] - scc[3*ak+0];
            const float b3y = scc[3*al+1] - scc[3*ak+1];
            const float b3z = scc[3*al+2] - scc[3*ak+2];
            const float n1x = b1y*b2z - b1z*b2y;
            const float n1y = b1z*b2x - b1x*b2z;
            const float n1z = b1x*b2y - b1y*b2x;
            const float n2x = b2y*b3z - b2z*b3y;
            const float n2y = b2z*b3x - b2x*b3z;
            const float n2z = b2x*b3y - b2y*b3x;
            const float inv = 1.0f / sqrtf(b2x*b2x + b2y*b2y + b2z*b2z + EPSV);
            const float bnx = b2x * inv, bny = b2y * inv, bnz = b2z * inv;
            const float m1x = n1y*bnz - n1z*bny;
            const float m1y = n1z*bnx - n1x*bnz;
            const float m1z = n1x*bny - n1y*bnx;
            const float phi = atan2f(m1x*n2x + m1y*n2y + m1z*n2z,
                                     n1x*n2x + n1y*n2y + n1z*n2z);
            eA += stt[tt * 2 + 0] * (1.0f + cosf(smu[tt] * phi - stt[tt * 2 + 1]));
        }
    }

    // ======== Reduction + disjoint plain stores ========
    for (int off = 32; off > 0; off >>= 1) {
        eA += __shfl_down(eA, off);
        eB += __shfl_down(eB, off);
    }
    if (l == 0) { sred[w * 2 + 0] = eA; sred[w * 2 + 1] = eB; }
    __syncthreads();
    if (tid == 0) {
        float rA = 0.f, rB = 0.f;
        for (int i = 0; i < WAVES; ++i) { rA += sred[i * 2]; rB += sred[i * 2 + 1]; }
        if (p) {
            out[s * 3 + 0] = opt_pars[0] * rA;   // bonds
            out[s * 3 + 1] = opt_pars[1] * rB;   // angles
        } else {
            out[s * 3 + 2] = opt_pars[2] * rA;   // torsions
        }
    }
}

extern "C" void kernel_launch(void* const* d_in, const int* in_sizes, int n_in,
                              void* d_out, int out_size, void* d_ws, size_t ws_size,
                              hipStream_t stream) {
    const float* F            = (const float*)d_in[0];
    // d_in[1] = lengths (constant, unused)
    const float* bond_type    = (const float*)d_in[2];
    const float* angle_type   = (const float*)d_in[3];
    const float* tor_type     = (const float*)d_in[4];
    const int*   multiplicity = (const int*)  d_in[5];
    const float* opt_pars     = (const float*)d_in[6];
    float* out = (float*)d_out;

    // Every out element written exactly once by plain stores -> no memset.
    local_energy_v14<<<dim3(BATCH * 2), dim3(THREADS), 0, stream>>>(
        F, bond_type, angle_type, tor_type, multiplicity, opt_pars, out);
}

// Round 15
// 156.857 us; speedup vs baseline: 1.0535x; 1.0068x over previous
//
#include <hip/hip_runtime.h>
#include <math.h>

#define BATCH    128
#define N_ATOMS  4096
#define NB       4095
#define NA       4094
#define NT       4093
#define FSTRIDE  184185                // floats per sample
#define ROWS     20465                 // rows of 9 floats per sample
#define CROWS    12288                 // coord elements (3*N_ATOMS)
#define BROWS    12285                 // bond elements  (3*NB)
#define AROWS    16376                 // angle elements (4*NA)
#define EPSV     1e-8f
#define THREADS  1024
#define WAVES    16
#define TPR      120                   // rows per tile (2 rows per lane)
#define T_A1     103                   // tiles 0..102: rows < 12360 (coords+bonds complete; tors 0..2471)
#define NT_PRE   2472                  // torsions complete after A1 (5i+4 < 12360)

// 4-byte-aligned float4 (row fields at float 9R+5 are dword-aligned only).
typedef float float4a __attribute__((ext_vector_type(4), aligned(4)));

__global__ __launch_bounds__(THREADS, 1) void
local_energy_v15(const float* __restrict__ F,
                 const float* __restrict__ bond_type,   // 15 x 2
                 const float* __restrict__ angle_type,  // 13 x 2
                 const float* __restrict__ tor_type,    // 25 x 2
                 const int*   __restrict__ multiplicity,// 25
                 const float* __restrict__ opt_pars,    // 47
                 float*       __restrict__ out)         // B x 3
{
    __shared__ float          scc[CROWS];
    __shared__ unsigned short sbB[BROWS + 1];
    __shared__ unsigned short sbA[AROWS];
    __shared__ unsigned short sbT[ROWS + 1];
    __shared__ float sbt[30], sat[26], stt[50], smu[25];
    __shared__ float sred[WAVES * 2];

    const int b   = blockIdx.x;
    const int x   = b & 7;             // XCD slot (twins share it -> L2/L3 dedup)
    const int g   = b >> 3;            // 0..31
    const int s   = (g & 15) * 8 + x;  // sample 0..127
    const int p   = g >> 4;            // 0: torsions   1: bonds + angles
    const int tid = threadIdx.x;
    const int w   = tid >> 6;
    const int l   = tid & 63;
    const size_t sbase = (size_t)s * FSTRIDE;

    if (tid < 30)                      sbt[tid]       = bond_type[tid];
    else if (tid >= 32 && tid < 58)    sat[tid - 32]  = angle_type[tid - 32];
    else if (tid >= 64 && tid < 114)   stt[tid - 64]  = tor_type[tid - 64];
    else if (tid >= 128 && tid < 153)  smu[tid - 128] = (float)multiplicity[tid - 128];

    // ======== Phase A1: all 16 waves stream tiles 0..102 (rows < 12360) ========
    // Row R: one dwordx4 at 9R+5 = (coord,bond,angle,tor)[R] -> LDS offset R.
    for (int t = w; t < T_A1; t += WAVES) {
        const int R0 = TPR * t + 2 * l;
        const int R1 = R0 + 1;
        float4a v0 = *(const float4a*)(F + sbase + (size_t)9 * R0 + 5);
        float4a v1 = *(const float4a*)(F + sbase + (size_t)9 * R1 + 5);

        if (R1 < CROWS) {                    // CROWS even: pair-uniform
            float2 c2; c2.x = v0.x; c2.y = v1.x;
            *(float2*)(scc + R0) = c2;
        }
        if (p) {
            if (R1 < BROWS) {
                unsigned pk = (unsigned)(unsigned short)(int)v0.y
                            | ((unsigned)(unsigned short)(int)v1.y << 16);
                *(unsigned*)(sbB + R0) = pk;
            } else if (R0 < BROWS) {
                sbB[R0] = (unsigned short)(int)v0.y;
            }
            {   // angle rows all < AROWS in A1 range
                unsigned pk = (unsigned)(unsigned short)(int)v0.z
                            | ((unsigned)(unsigned short)(int)v1.z << 16);
                *(unsigned*)(sbA + R0) = pk;
            }
        } else {
            unsigned pk = (unsigned)(unsigned short)(int)v0.w
                        | ((unsigned)(unsigned short)(int)v1.w << 16);
            *(unsigned*)(sbT + R0) = pk;
        }
    }
    __syncthreads();   // coords complete; bond rows complete; tor rows < 12360 complete

    float eA = 0.f, eB = 0.f;          // p0: eA=tor | p1: eA=bond, eB=angle

    // ======== Phase A2 (waves 0-7): stream tail tiles ||| (waves 8-15): compute prefix ========
    if (w < 8) {
        const int tmax = p ? 137 : 171;      // p1: rows to 16440 (covers AROWS); p0: all rows
        for (int t = T_A1 + w; t < tmax; t += 8) {
            const int R0 = TPR * t + 2 * l;
            const int R1 = R0 + 1;
            float4a v0, v1;
            const bool ok0 = (R0 < ROWS);
            const bool ok1 = (R1 < ROWS);
            if (ok0) v0 = *(const float4a*)(F + sbase + (size_t)9 * R0 + 5);
            if (ok1) v1 = *(const float4a*)(F + sbase + (size_t)9 * R1 + 5);
            if (p) {                          // only angle rows remain (R >= 12360)
                if (R1 < AROWS) {
                    unsigned pk = (unsigned)(unsigned short)(int)v0.z
                                | ((unsigned)(unsigned short)(int)v1.z << 16);
                    *(unsigned*)(sbA + R0) = pk;
                } else if (R0 < AROWS) {
                    sbA[R0] = (unsigned short)(int)v0.z;
                }
            } else {                          // only torsion rows remain
                if (ok1) {
                    unsigned pk = (unsigned)(unsigned short)(int)v0.w
                                | ((unsigned)(unsigned short)(int)v1.w << 16);
                    *(unsigned*)(sbT + R0) = pk;
                } else if (ok0) {
                    sbT[R0] = (unsigned short)(int)v0.w;
                }
            }
        }
    } else {
        const int ctid = tid - 512;           // 0..511
        if (p) {
            // all bonds are ready (rows < 12285 < 12360)
            for (int i = ctid; i < NB; i += 512) {
                const int a0 = sbB[3 * i + 0];
                const int a1 = sbB[3 * i + 1];
                const int bt = sbB[3 * i + 2];
                const float dx = scc[3 * a0 + 0] - scc[3 * a1 + 0];
                const float dy = scc[3 * a0 + 1] - scc[3 * a1 + 1];
                const float dz = scc[3 * a0 + 2] - scc[3 * a1 + 2];
                const float r  = sqrtf(dx * dx + dy * dy + dz * dz + EPSV);
                const float t0 = r - sbt[bt * 2 + 1];
                eA += sbt[bt * 2 + 0] * t0 * t0;
            }
        } else {
            // torsions 0..2471 are ready (rows 5i+4 < 12360)
            for (int i = ctid; i < NT_PRE; i += 512) {
                const int ai = sbT[5 * i + 0];
                const int aj = sbT[5 * i + 1];
                const int ak = sbT[5 * i + 2];
                const int al = sbT[5 * i + 3];
                const int tt = sbT[5 * i + 4];
                const float b1x = scc[3*aj+0] - scc[3*ai+0];
                const float b1y = scc[3*aj+1] - scc[3*ai+1];
                const float b1z = scc[3*aj+2] - scc[3*ai+2];
                const float b2x = scc[3*ak+0] - scc[3*aj+0];
                const float b2y = scc[3*ak+1] - scc[3*aj+1];
                const float b2z = scc[3*ak+2] - scc[3*aj+2];
                const float b3x = scc[3*al+0] - scc[3*ak+0];
                const float b3y = scc[3*al+1] - scc[3*ak+1];
                const float b3z = scc[3*al+2] - scc[3*ak+2];
                const float n1x = b1y*b2z - b1z*b2y;
                const float n1y = b1z*b2x - b1x*b2z;
                const float n1z = b1x*b2y - b1y*b2x;
                const float n2x = b2y*b3z - b2z*b3y;
                const float n2y = b2z*b3x - b2x*b3z;
                const float n2z = b2x*b3y - b2y*b3x;
                const float inv = 1.0f / sqrtf(b2x*b2x + b2y*b2y + b2z*b2z + EPSV);
                const float bnx = b2x * inv, bny = b2y * inv, bnz = b2z * inv;
                const float m1x = n1y*bnz - n1z*bny;
                const float m1y = n1z*bnx - n1x*bnz;
                const float m1z = n1x*bny - n1y*bnx;
                const float phi = atan2f(m1x*n2x + m1y*n2y + m1z*n2z,
                                         n1x*n2x + n1y*n2y + n1z*n2z);
                eA += stt[tt * 2 + 0] * (1.0f + cosf(smu[tt] * phi - stt[tt * 2 + 1]));
            }
        }
    }
    __syncthreads();

    // ======== Final stage: all 16 waves finish the remainder ========
    if (p) {
        for (int i = tid; i < NA; i += THREADS) {
            const int a0 = sbA[4 * i + 0];
            const int a1 = sbA[4 * i + 1];
            const int a2 = sbA[4 * i + 2];
            const int at = sbA[4 * i + 3];
            const float v1x = scc[3 * a0 + 0] - scc[3 * a1 + 0];
            const float v1y = scc[3 * a0 + 1] - scc[3 * a1 + 1];
            const float v1z = scc[3 * a0 + 2] - scc[3 * a1 + 2];
            const float v2x = scc[3 * a2 + 0] - scc[3 * a1 + 0];
            const float v2y = scc[3 * a2 + 1] - scc[3 * a1 + 1];
            const float v2z = scc[3 * a2 + 2] - scc[3 * a1 + 2];
            const float d12 = v1x * v2x + v1y * v2y + v1z * v2z;
            const float n1  = sqrtf(v1x * v1x + v1y * v1y + v1z * v1z + EPSV);
            const float n2  = sqrtf(v2x * v2x + v2y * v2y + v2z * v2z + EPSV);
            float cosang = d12 / (n1 * n2);
            cosang = fminf(fmaxf(cosang, -1.0f + 1e-6f), 1.0f - 1e-6f);
            const float t0 = acosf(cosang) - sat[at * 2 + 1];
            eB += sat[at * 2 + 0] * t0 * t0;
        }
    } else {
        for (int i = NT_PRE + tid; i < NT; i += THREADS) {
            const int ai = sbT[5 * i + 0];
            const int aj = sbT[5 * i + 1];
            const int ak = sbT[5 * i + 2];
            const int al = sbT[5 * i + 3];
            const int tt = sbT[5 * i + 4];
            const float b1x = scc[3*aj+0] - scc[3*ai+0];
            const float b1y = scc[3*aj+1] - scc[3*ai+1];
            const float b1z = scc[3*aj+2] - scc[3*ai+2];
            const float b2x = scc[3*ak+0] - scc[3*aj+0];
            const float b2y = scc[3*ak+1] - scc[3*aj+1];
            const float b2z = scc[3*ak+2] - scc[3*aj+2];
            const float b3x = scc[3*al+0] - scc[3*ak+0];
            const float b3y = scc[3*al+1] - scc[3*ak+1];
            const float b3z = scc[3*al+2] - scc[3*ak+2];
            const float n1x = b1y*b2z - b1z*b2y;
            const float n1y = b1z*b2x - b1x*b2z;
            const float n1z = b1x*b2y - b1y*b2x;
            const float n2x = b2y*b3z - b2z*b3y;
            const float n2y = b2z*b3x - b2x*b3z;
            const float n2z = b2x*b3y - b2y*b3x;
            const float inv = 1.0f / sqrtf(b2x*b2x + b2y*b2y + b2z*b2z + EPSV);
            const float bnx = b2x * inv, bny = b2y * inv, bnz = b2z * inv;
            const float m1x = n1y*bnz - n1z*bny;
            const float m1y = n1z*bnx - n1x*bnz;
            const float m1z = n1x*bny - n1y*bnx;
            const float phi = atan2f(m1x*n2x + m1y*n2y + m1z*n2z,
                                     n1x*n2x + n1y*n2y + n1z*n2z);
            eA += stt[tt * 2 + 0] * (1.0f + cosf(smu[tt] * phi - stt[tt * 2 + 1]));
        }
    }

    // ======== Reduction + disjoint plain stores ========
    for (int off = 32; off > 0; off >>= 1) {
        eA += __shfl_down(eA, off);
        eB += __shfl_down(eB, off);
    }
    if (l == 0) { sred[w * 2 + 0] = eA; sred[w * 2 + 1] = eB; }
    __syncthreads();
    if (tid == 0) {
        float rA = 0.f, rB = 0.f;
        for (int i = 0; i < WAVES; ++i) { rA += sred[i * 2]; rB += sred[i * 2 + 1]; }
        if (p) {
            out[s * 3 + 0] = opt_pars[0] * rA;   // bonds
            out[s * 3 + 1] = opt_pars[1] * rB;   // angles
        } else {
            out[s * 3 + 2] = opt_pars[2] * rA;   // torsions
        }
    }
}

extern "C" void kernel_launch(void* const* d_in, const int* in_sizes, int n_in,
                              void* d_out, int out_size, void* d_ws, size_t ws_size,
                              hipStream_t stream) {
    const float* F            = (const float*)d_in[0];
    // d_in[1] = lengths (constant, unused)
    const float* bond_type    = (const float*)d_in[2];
    const float* angle_type   = (const float*)d_in[3];
    const float* tor_type     = (const float*)d_in[4];
    const int*   multiplicity = (const int*)  d_in[5];
    const float* opt_pars     = (const float*)d_in[6];
    float* out = (float*)d_out;

    // Every out element written exactly once by plain stores -> no memset.
    local_energy_v15<<<dim3(BATCH * 2), dim3(THREADS), 0, stream>>>(
        F, bond_type, angle_type, tor_type, multiplicity, opt_pars, out);
}